// Round 2
// baseline (721.449 us; speedup 1.0000x reference)
//
#include <hip/hip_runtime.h>
#include <stdint.h>

#define BN_EPS 1e-5f

typedef __bf16   bf16x8 __attribute__((ext_vector_type(8)));
typedef float    f32x4  __attribute__((ext_vector_type(4)));
typedef unsigned u32x4  __attribute__((ext_vector_type(4)));
typedef unsigned u32x2  __attribute__((ext_vector_type(2)));

union Frag {
  u32x4 q;
  bf16x8 b;
  unsigned short s[8];
  unsigned u[4];
};

static __device__ __forceinline__ unsigned short f2bf(float f) {
  union { float f; unsigned u; } v; v.f = f;
  unsigned r = (v.u + 0x7fffu + ((v.u >> 16) & 1u)) >> 16;   // RNE
  return (unsigned short)r;
}
static __device__ __forceinline__ float bflo(unsigned u) {
  union { unsigned u; float f; } v; v.u = u << 16; return v.f;
}
static __device__ __forceinline__ float bfhi(unsigned u) {
  union { unsigned u; float f; } v; v.u = u & 0xffff0000u; return v.f;
}

// ---------------- kernel 1: per-node projections -------------------
// T1[n][k] = sum_d z[n][d]*W1[d][k] + kv[k]   (kv = c @ W1[128:132] + b1 folded in)
// T2[n][k] = sum_d z[n][d]*W1[64+d][k]
__global__ __launch_bounds__(256) void k_nodeproj(
    const float* __restrict__ z, const float* __restrict__ c,
    const float* __restrict__ W1, const float* __restrict__ b1,
    unsigned short* __restrict__ T1, unsigned short* __restrict__ T2,
    int n_nodes) {
  __shared__ float Wl[64][128];   // 32 KB
  __shared__ float kv[128];
  const int t = threadIdx.x;
  if (t < 128) {
    float acc = b1[t];
    #pragma unroll
    for (int q = 0; q < 4; ++q) acc += c[q] * W1[(128 + q) * 128 + t];
    kv[t] = acc;
  }
  for (int i = t; i < 8192; i += 256) Wl[i >> 7][i & 127] = W1[i];
  __syncthreads();
  const int n = blockIdx.x * 256 + t;
  const bool act = (n < n_nodes);
  float zr[64];
  if (act) {
    const f32x4* zp = (const f32x4*)(z + (size_t)n * 64);
    #pragma unroll
    for (int j = 0; j < 16; ++j) {
      f32x4 v = zp[j];
      zr[4*j+0] = v[0]; zr[4*j+1] = v[1]; zr[4*j+2] = v[2]; zr[4*j+3] = v[3];
    }
  }
  if (act) {
    for (int k8 = 0; k8 < 16; ++k8) {
      float acc[8];
      f32x4 k0 = *(const f32x4*)&kv[k8*8];
      f32x4 k1 = *(const f32x4*)&kv[k8*8+4];
      acc[0]=k0[0]; acc[1]=k0[1]; acc[2]=k0[2]; acc[3]=k0[3];
      acc[4]=k1[0]; acc[5]=k1[1]; acc[6]=k1[2]; acc[7]=k1[3];
      #pragma unroll
      for (int d = 0; d < 64; ++d) {
        float zd = zr[d];
        f32x4 wa = *(const f32x4*)&Wl[d][k8*8];
        f32x4 wb = *(const f32x4*)&Wl[d][k8*8+4];
        acc[0] += zd*wa[0]; acc[1] += zd*wa[1]; acc[2] += zd*wa[2]; acc[3] += zd*wa[3];
        acc[4] += zd*wb[0]; acc[5] += zd*wb[1]; acc[6] += zd*wb[2]; acc[7] += zd*wb[3];
      }
      Frag f;
      #pragma unroll
      for (int j = 0; j < 8; ++j) f.s[j] = f2bf(acc[j]);
      *(u32x4*)(T1 + (size_t)n*128 + k8*8) = f.q;
    }
  }
  __syncthreads();
  for (int i = t; i < 8192; i += 256) Wl[i >> 7][i & 127] = W1[8192 + i];
  __syncthreads();
  if (act) {
    for (int k8 = 0; k8 < 16; ++k8) {
      float acc[8] = {0,0,0,0,0,0,0,0};
      #pragma unroll
      for (int d = 0; d < 64; ++d) {
        float zd = zr[d];
        f32x4 wa = *(const f32x4*)&Wl[d][k8*8];
        f32x4 wb = *(const f32x4*)&Wl[d][k8*8+4];
        acc[0] += zd*wa[0]; acc[1] += zd*wa[1]; acc[2] += zd*wa[2]; acc[3] += zd*wa[3];
        acc[4] += zd*wb[0]; acc[5] += zd*wb[1]; acc[6] += zd*wb[2]; acc[7] += zd*wb[3];
      }
      Frag f;
      #pragma unroll
      for (int j = 0; j < 8; ++j) f.s[j] = f2bf(acc[j]);
      *(u32x4*)(T2 + (size_t)n*128 + k8*8) = f.q;
    }
  }
}

// ---------------- kernel 2: BN statistics pass ---------------------
// h1[e][f] = relu(T1[src[e]][f] + T2[dst[e]][f]); accumulate sum/sumsq per f.
// Wave processes 2 edges/iter; lane owns features col*4..col*4+3 exclusively.
__global__ __launch_bounds__(256) void k_stats(
    const int* __restrict__ ei, const unsigned short* __restrict__ T1,
    const unsigned short* __restrict__ T2, float* __restrict__ partial,
    int E, int npairs) {
  __shared__ float red[4][256];
  const int t = threadIdx.x;
  const int w = t >> 6, l = t & 63;
  const int half = l >> 5, col = l & 31;
  float sm0=0,sm1=0,sm2=0,sm3=0, sq0=0,sq1=0,sq2=0,sq3=0;
  const int nw = gridDim.x * 4;
  for (int p = blockIdx.x * 4 + w; p < npairs; p += nw) {
    int e = 2*p + half;
    int s = ei[e];
    int d = ei[E + e];
    u32x2 ua = *(const u32x2*)(T1 + (size_t)s*128 + col*4);
    u32x2 ub = *(const u32x2*)(T2 + (size_t)d*128 + col*4);
    float h0 = fmaxf(bflo(ua[0]) + bflo(ub[0]), 0.f);
    float h1 = fmaxf(bfhi(ua[0]) + bfhi(ub[0]), 0.f);
    float h2 = fmaxf(bflo(ua[1]) + bflo(ub[1]), 0.f);
    float h3 = fmaxf(bfhi(ua[1]) + bfhi(ub[1]), 0.f);
    sm0 += h0; sm1 += h1; sm2 += h2; sm3 += h3;
    sq0 += h0*h0; sq1 += h1*h1; sq2 += h2*h2; sq3 += h3*h3;
  }
  sm0 += __shfl_xor(sm0, 32, 64); sm1 += __shfl_xor(sm1, 32, 64);
  sm2 += __shfl_xor(sm2, 32, 64); sm3 += __shfl_xor(sm3, 32, 64);
  sq0 += __shfl_xor(sq0, 32, 64); sq1 += __shfl_xor(sq1, 32, 64);
  sq2 += __shfl_xor(sq2, 32, 64); sq3 += __shfl_xor(sq3, 32, 64);
  if (l < 32) {
    red[w][col*4+0] = sm0; red[w][col*4+1] = sm1;
    red[w][col*4+2] = sm2; red[w][col*4+3] = sm3;
    red[w][128+col*4+0] = sq0; red[w][128+col*4+1] = sq1;
    red[w][128+col*4+2] = sq2; red[w][128+col*4+3] = sq3;
  }
  __syncthreads();
  partial[(size_t)blockIdx.x * 256 + t] =
      red[0][t] + red[1][t] + red[2][t] + red[3][t];
}

// ---------------- kernel 3: finalize BN + fold into W2 -------------
// a = gamma*rsqrt(var+eps); bb = beta - mean*a
// W2t[j][i] = a[i]*W2[i][j]  (bf16, transposed);  b2p[j] = b2[j] + sum_i bb[i]*W2[i][j]
__global__ __launch_bounds__(256) void k_finalize(
    const float* __restrict__ partial, int nb,
    const float* __restrict__ gamma, const float* __restrict__ beta,
    const float* __restrict__ W2, const float* __restrict__ b2,
    unsigned short* __restrict__ W2t, float* __restrict__ b2p, float Einv) {
  __shared__ float stat[256];
  __shared__ float aj[128], bbj[128];
  const int t = threadIdx.x;
  float s = 0.f;
  for (int b = 0; b < nb; ++b) s += partial[(size_t)b*256 + t];
  stat[t] = s;
  __syncthreads();
  if (t < 128) {
    float mean = stat[t] * Einv;
    float var  = stat[128 + t] * Einv - mean * mean;
    float a = gamma[t] * rsqrtf(var + BN_EPS);
    aj[t] = a;
    bbj[t] = beta[t] - mean * a;
  }
  __syncthreads();
  for (int cidx = t; cidx < 16384; cidx += 256) {
    int j = cidx >> 7;     // output column = W2t row
    int i = cidx & 127;    // input feature
    W2t[j*128 + i] = f2bf(aj[i] * W2[i*128 + j]);
  }
  if (t < 128) {
    float acc = b2[t];
    for (int i = 0; i < 128; ++i) acc += bbj[i] * W2[i*128 + t];
    b2p[t] = acc;
  }
}

// ---------------- kernel 4: per-edge MFMA pass ---------------------
// Wave: 32 edges x 128 outputs. A-frags (h1, bf16) built in registers from
// gathers; B (W2t) in LDS with XOR swizzle; fused relu + W3 dot epilogue.
__global__ __launch_bounds__(256) void k_edge(
    const int* __restrict__ ei, const unsigned short* __restrict__ T1,
    const unsigned short* __restrict__ T2, const unsigned short* __restrict__ W2t,
    const float* __restrict__ b2p, const float* __restrict__ W3,
    const float* __restrict__ b3, float* __restrict__ out,
    int E, int ntiles) {
  __shared__ u32x4 w2l[2048];   // 32 KB, XOR-swizzled [n][k] bf16
  const int t = threadIdx.x;
  for (int cchunk = t; cchunk < 2048; cchunk += 256) {
    int n = cchunk >> 4;
    int koff = (cchunk & 15) << 4;               // byte offset within 256B row
    int swz = koff ^ ((n & 7) << 4);
    w2l[n*16 + (swz >> 4)] =
        *(const u32x4*)((const char*)W2t + (size_t)n*256 + koff);
  }
  __syncthreads();
  const int w = t >> 6, l = t & 63;
  const int lm = l & 15, lg = l >> 4;
  float b2r[8], w3r[8];
  #pragma unroll
  for (int nt = 0; nt < 8; ++nt) {
    b2r[nt] = b2p[nt*16 + lm];
    w3r[nt] = W3[nt*16 + lm];
  }
  const float b3v = *b3;
  for (int tile = blockIdx.x; tile < ntiles; tile += gridDim.x) {
    const int ebase = tile*128 + w*32;
    int src0 = ei[ebase + lm],      src1 = ei[ebase + 16 + lm];
    int dst0 = ei[E + ebase + lm],  dst1 = ei[E + ebase + 16 + lm];
    // Build A fragments: a[mt][s] holds h1[edge lm (+16*mt)][k = s*32+lg*8 .. +8]
    Frag a[2][4];
    #pragma unroll
    for (int s = 0; s < 4; ++s) {
      const int off = s*64 + lg*16;  // byte offset into 256B row
      #pragma unroll
      for (int mt = 0; mt < 2; ++mt) {
        int sn = mt ? src1 : src0;
        int dn = mt ? dst1 : dst0;
        u32x4 ua = *(const u32x4*)((const char*)T1 + (size_t)sn*256 + off);
        u32x4 ub = *(const u32x4*)((const char*)T2 + (size_t)dn*256 + off);
        Frag fa;
        #pragma unroll
        for (int q = 0; q < 4; ++q) {
          float v0 = fmaxf(bflo(ua[q]) + bflo(ub[q]), 0.f);
          float v1 = fmaxf(bfhi(ua[q]) + bfhi(ub[q]), 0.f);
          fa.s[2*q]   = f2bf(v0);
          fa.s[2*q+1] = f2bf(v1);
        }
        a[mt][s].q = fa.q;
      }
    }
    // MFMA: acc[mt][nt] = h1_tile(16x128) @ W2t'(128x16 per nt)
    f32x4 acc[2][8];
    #pragma unroll
    for (int mt = 0; mt < 2; ++mt)
      #pragma unroll
      for (int nt = 0; nt < 8; ++nt) {
        f32x4 zed = {0.f, 0.f, 0.f, 0.f};
        acc[mt][nt] = zed;
      }
    #pragma unroll
    for (int nt = 0; nt < 8; ++nt) {
      #pragma unroll
      for (int s = 0; s < 4; ++s) {
        int idx16 = (nt*16 + lm)*16 + (((s*4 + lg)) ^ (lm & 7));
        Frag bf; bf.q = w2l[idx16];
        acc[0][nt] = __builtin_amdgcn_mfma_f32_16x16x32_bf16(a[0][s].b, bf.b, acc[0][nt], 0, 0, 0);
        acc[1][nt] = __builtin_amdgcn_mfma_f32_16x16x32_bf16(a[1][s].b, bf.b, acc[1][nt], 0, 0, 0);
      }
    }
    // Epilogue: h2 = relu(acc + b2p); logit = sum_n h2*W3 (+b3)
    #pragma unroll
    for (int mt = 0; mt < 2; ++mt) {
      #pragma unroll
      for (int r = 0; r < 4; ++r) {
        float sum = 0.f;
        #pragma unroll
        for (int nt = 0; nt < 8; ++nt) {
          float h2 = fmaxf(acc[mt][nt][r] + b2r[nt], 0.f);
          sum += h2 * w3r[nt];
        }
        sum += __shfl_xor(sum, 1, 64);
        sum += __shfl_xor(sum, 2, 64);
        sum += __shfl_xor(sum, 4, 64);
        sum += __shfl_xor(sum, 8, 64);
        if (lm == 0) out[ebase + mt*16 + lg*4 + r] = sum + b3v;
      }
    }
  }
}

extern "C" void kernel_launch(void* const* d_in, const int* in_sizes, int n_in,
                              void* d_out, int out_size, void* d_ws, size_t ws_size,
                              hipStream_t stream) {
  const float* z     = (const float*)d_in[0];
  const int*   ei    = (const int*)d_in[1];
  const float* c     = (const float*)d_in[2];
  const float* W1    = (const float*)d_in[3];
  const float* b1    = (const float*)d_in[4];
  const float* gamma = (const float*)d_in[5];
  const float* beta  = (const float*)d_in[6];
  const float* W2    = (const float*)d_in[7];
  const float* b2    = (const float*)d_in[8];
  const float* W3    = (const float*)d_in[9];
  const float* b3    = (const float*)d_in[10];
  float* out = (float*)d_out;

  const int n_nodes = in_sizes[0] / 64;   // 50000
  const int E       = in_sizes[1] / 2;    // 1600000

  const int NB2 = 1024;   // stats blocks
  const int NB4 = 1024;   // edge blocks

  char* ws = (char*)d_ws;
  const size_t t1b = (size_t)n_nodes * 128 * 2;           // bf16 table bytes
  unsigned short* T1 = (unsigned short*)ws;
  unsigned short* T2 = (unsigned short*)(ws + t1b);
  float* partial     = (float*)(ws + 2*t1b);              // NB2*256 f32
  unsigned short* W2t= (unsigned short*)(ws + 2*t1b + (size_t)NB2*1024);
  float* b2p         = (float*)(ws + 2*t1b + (size_t)NB2*1024 + 32768);

  k_nodeproj<<<(n_nodes + 255)/256, 256, 0, stream>>>(z, c, W1, b1, T1, T2, n_nodes);
  k_stats<<<NB2, 256, 0, stream>>>(ei, T1, T2, partial, E, E/2);
  k_finalize<<<1, 256, 0, stream>>>(partial, NB2, gamma, beta, W2, b2, W2t, b2p, 1.0f/(float)E);
  k_edge<<<NB4, 256, 0, stream>>>(ei, T1, T2, W2t, b2p, W3, b3, out, E, E/128);
}

// Round 3
// 552.685 us; speedup vs baseline: 1.3054x; 1.3054x over previous
//
#include <hip/hip_runtime.h>
#include <stdint.h>

#define BN_EPS 1e-5f

typedef __bf16   bf16x8 __attribute__((ext_vector_type(8)));
typedef float    f32x4  __attribute__((ext_vector_type(4)));
typedef unsigned u32x4  __attribute__((ext_vector_type(4)));
typedef unsigned u32x2  __attribute__((ext_vector_type(2)));

union Frag {
  u32x4 q;
  bf16x8 b;
  unsigned short s[8];
  unsigned u[4];
};

static __device__ __forceinline__ unsigned short f2bf(float f) {
  union { float f; unsigned u; } v; v.f = f;
  unsigned r = (v.u + 0x7fffu + ((v.u >> 16) & 1u)) >> 16;   // RNE
  return (unsigned short)r;
}
static __device__ __forceinline__ float bflo(unsigned u) {
  union { unsigned u; float f; } v; v.u = u << 16; return v.f;
}
static __device__ __forceinline__ float bfhi(unsigned u) {
  union { unsigned u; float f; } v; v.u = u & 0xffff0000u; return v.f;
}

// ---------------- kernel 1: per-node projections -------------------
// T1[n][k] = sum_d z[n][d]*W1[d][k] + kv[k]   (kv = c @ W1[128:132] + b1 folded in)
// T2[n][k] = sum_d z[n][d]*W1[64+d][k]
__global__ __launch_bounds__(256) void k_nodeproj(
    const float* __restrict__ z, const float* __restrict__ c,
    const float* __restrict__ W1, const float* __restrict__ b1,
    unsigned short* __restrict__ T1, unsigned short* __restrict__ T2,
    int n_nodes) {
  __shared__ float Wl[64][128];   // 32 KB
  __shared__ float kv[128];
  const int t = threadIdx.x;
  if (t < 128) {
    float acc = b1[t];
    #pragma unroll
    for (int q = 0; q < 4; ++q) acc += c[q] * W1[(128 + q) * 128 + t];
    kv[t] = acc;
  }
  for (int i = t; i < 8192; i += 256) Wl[i >> 7][i & 127] = W1[i];
  __syncthreads();
  const int n = blockIdx.x * 256 + t;
  const bool act = (n < n_nodes);
  float zr[64];
  if (act) {
    const f32x4* zp = (const f32x4*)(z + (size_t)n * 64);
    #pragma unroll
    for (int j = 0; j < 16; ++j) {
      f32x4 v = zp[j];
      zr[4*j+0] = v[0]; zr[4*j+1] = v[1]; zr[4*j+2] = v[2]; zr[4*j+3] = v[3];
    }
  }
  if (act) {
    for (int k8 = 0; k8 < 16; ++k8) {
      float acc[8];
      f32x4 k0 = *(const f32x4*)&kv[k8*8];
      f32x4 k1 = *(const f32x4*)&kv[k8*8+4];
      acc[0]=k0[0]; acc[1]=k0[1]; acc[2]=k0[2]; acc[3]=k0[3];
      acc[4]=k1[0]; acc[5]=k1[1]; acc[6]=k1[2]; acc[7]=k1[3];
      #pragma unroll
      for (int d = 0; d < 64; ++d) {
        float zd = zr[d];
        f32x4 wa = *(const f32x4*)&Wl[d][k8*8];
        f32x4 wb = *(const f32x4*)&Wl[d][k8*8+4];
        acc[0] += zd*wa[0]; acc[1] += zd*wa[1]; acc[2] += zd*wa[2]; acc[3] += zd*wa[3];
        acc[4] += zd*wb[0]; acc[5] += zd*wb[1]; acc[6] += zd*wb[2]; acc[7] += zd*wb[3];
      }
      Frag f;
      #pragma unroll
      for (int j = 0; j < 8; ++j) f.s[j] = f2bf(acc[j]);
      *(u32x4*)(T1 + (size_t)n*128 + k8*8) = f.q;
    }
  }
  __syncthreads();
  for (int i = t; i < 8192; i += 256) Wl[i >> 7][i & 127] = W1[8192 + i];
  __syncthreads();
  if (act) {
    for (int k8 = 0; k8 < 16; ++k8) {
      float acc[8] = {0,0,0,0,0,0,0,0};
      #pragma unroll
      for (int d = 0; d < 64; ++d) {
        float zd = zr[d];
        f32x4 wa = *(const f32x4*)&Wl[d][k8*8];
        f32x4 wb = *(const f32x4*)&Wl[d][k8*8+4];
        acc[0] += zd*wa[0]; acc[1] += zd*wa[1]; acc[2] += zd*wa[2]; acc[3] += zd*wa[3];
        acc[4] += zd*wb[0]; acc[5] += zd*wb[1]; acc[6] += zd*wb[2]; acc[7] += zd*wb[3];
      }
      Frag f;
      #pragma unroll
      for (int j = 0; j < 8; ++j) f.s[j] = f2bf(acc[j]);
      *(u32x4*)(T2 + (size_t)n*128 + k8*8) = f.q;
    }
  }
}

// ---------------- kernel 2: BN statistics pass ---------------------
// h1[e][f] = relu(T1[src[e]][f] + T2[dst[e]][f]); accumulate sum/sumsq per f.
// Wave processes 2 edges/iter; lane owns features col*4..col*4+3 exclusively.
__global__ __launch_bounds__(256) void k_stats(
    const int* __restrict__ ei, const unsigned short* __restrict__ T1,
    const unsigned short* __restrict__ T2, float* __restrict__ partial,
    int E, int npairs) {
  __shared__ float red[4][256];
  const int t = threadIdx.x;
  const int w = t >> 6, l = t & 63;
  const int half = l >> 5, col = l & 31;
  float sm0=0,sm1=0,sm2=0,sm3=0, sq0=0,sq1=0,sq2=0,sq3=0;
  const int nw = gridDim.x * 4;
  for (int p = blockIdx.x * 4 + w; p < npairs; p += nw) {
    int e = 2*p + half;
    int s = ei[e];
    int d = ei[E + e];
    u32x2 ua = *(const u32x2*)(T1 + (size_t)s*128 + col*4);
    u32x2 ub = *(const u32x2*)(T2 + (size_t)d*128 + col*4);
    float h0 = fmaxf(bflo(ua[0]) + bflo(ub[0]), 0.f);
    float h1 = fmaxf(bfhi(ua[0]) + bfhi(ub[0]), 0.f);
    float h2 = fmaxf(bflo(ua[1]) + bflo(ub[1]), 0.f);
    float h3 = fmaxf(bfhi(ua[1]) + bfhi(ub[1]), 0.f);
    sm0 += h0; sm1 += h1; sm2 += h2; sm3 += h3;
    sq0 += h0*h0; sq1 += h1*h1; sq2 += h2*h2; sq3 += h3*h3;
  }
  sm0 += __shfl_xor(sm0, 32, 64); sm1 += __shfl_xor(sm1, 32, 64);
  sm2 += __shfl_xor(sm2, 32, 64); sm3 += __shfl_xor(sm3, 32, 64);
  sq0 += __shfl_xor(sq0, 32, 64); sq1 += __shfl_xor(sq1, 32, 64);
  sq2 += __shfl_xor(sq2, 32, 64); sq3 += __shfl_xor(sq3, 32, 64);
  if (l < 32) {
    red[w][col*4+0] = sm0; red[w][col*4+1] = sm1;
    red[w][col*4+2] = sm2; red[w][col*4+3] = sm3;
    red[w][128+col*4+0] = sq0; red[w][128+col*4+1] = sq1;
    red[w][128+col*4+2] = sq2; red[w][128+col*4+3] = sq3;
  }
  __syncthreads();
  partial[(size_t)blockIdx.x * 256 + t] =
      red[0][t] + red[1][t] + red[2][t] + red[3][t];
}

// ---------------- kernel 3: finalize BN + fold into W2 -------------
// One 1024-thread block (16 waves).
// Phase A: reduce partial[nb][256] -> stat[256], 4-way row-split + LDS tree.
// Phase B: aj = gamma*rsqrt(var+eps); bbj = beta - mean*aj
// Phase C: W2t[j][i] = aj[i]*W2[i][j]  (coalesced reads, scattered 2B writes)
//          b2p[j]   = b2[j] + sum_i bbj[i]*W2[i][j]  (8-way i-split + LDS tree)
__global__ __launch_bounds__(1024) void k_finalize(
    const float* __restrict__ partial, int nb,
    const float* __restrict__ gamma, const float* __restrict__ beta,
    const float* __restrict__ W2, const float* __restrict__ b2,
    unsigned short* __restrict__ W2t, float* __restrict__ b2p, float Einv) {
  __shared__ float red[4][256];
  __shared__ float stat[256];
  __shared__ float aj[128], bbj[128];
  __shared__ float bacc[8][128];
  const int t = threadIdx.x;
  const int slot = t & 255, g = t >> 8;           // g = 0..3
  float s = 0.f;
  for (int b = g; b < nb; b += 4) s += partial[(size_t)b * 256 + slot];
  red[g][slot] = s;
  __syncthreads();
  if (t < 256) stat[t] = red[0][t] + red[1][t] + red[2][t] + red[3][t];
  __syncthreads();
  if (t < 128) {
    float mean = stat[t] * Einv;
    float var  = stat[128 + t] * Einv - mean * mean;
    float a = gamma[t] * rsqrtf(var + BN_EPS);
    aj[t] = a;
    bbj[t] = beta[t] - mean * a;
  }
  __syncthreads();
  // W2t: 16384 elems; consecutive t -> consecutive j -> coalesced W2 reads
  for (int cidx = t; cidx < 16384; cidx += 1024) {
    int i = cidx >> 7;     // input feature (W2 row)
    int j = cidx & 127;    // output column (W2t row)
    W2t[j * 128 + i] = f2bf(aj[i] * W2[cidx]);
  }
  // b2p GEMV: col = t&127, group g2 handles 16 i's (coalesced W2 reads)
  {
    const int col = t & 127, g2 = t >> 7;         // g2 = 0..7
    float acc = 0.f;
    #pragma unroll
    for (int q = 0; q < 16; ++q) {
      int i = g2 * 16 + q;
      acc += bbj[i] * W2[i * 128 + col];
    }
    bacc[g2][col] = acc;
  }
  __syncthreads();
  if (t < 128) {
    float a = b2[t];
    #pragma unroll
    for (int g3 = 0; g3 < 8; ++g3) a += bacc[g3][t];
    b2p[t] = a;
  }
}

// ---------------- kernel 4: per-edge MFMA pass ---------------------
// Wave: 32 edges x 128 outputs. A-frags (h1, bf16) built in registers from
// gathers; B (W2t) in LDS with XOR swizzle; fused relu + W3 dot epilogue.
__global__ __launch_bounds__(256) void k_edge(
    const int* __restrict__ ei, const unsigned short* __restrict__ T1,
    const unsigned short* __restrict__ T2, const unsigned short* __restrict__ W2t,
    const float* __restrict__ b2p, const float* __restrict__ W3,
    const float* __restrict__ b3, float* __restrict__ out,
    int E, int ntiles) {
  __shared__ u32x4 w2l[2048];   // 32 KB, XOR-swizzled [n][k] bf16
  const int t = threadIdx.x;
  for (int cchunk = t; cchunk < 2048; cchunk += 256) {
    int n = cchunk >> 4;
    int koff = (cchunk & 15) << 4;               // byte offset within 256B row
    int swz = koff ^ ((n & 7) << 4);
    w2l[n*16 + (swz >> 4)] =
        *(const u32x4*)((const char*)W2t + (size_t)n*256 + koff);
  }
  __syncthreads();
  const int w = t >> 6, l = t & 63;
  const int lm = l & 15, lg = l >> 4;
  float b2r[8], w3r[8];
  #pragma unroll
  for (int nt = 0; nt < 8; ++nt) {
    b2r[nt] = b2p[nt*16 + lm];
    w3r[nt] = W3[nt*16 + lm];
  }
  const float b3v = *b3;
  for (int tile = blockIdx.x; tile < ntiles; tile += gridDim.x) {
    const int ebase = tile*128 + w*32;
    int src0 = ei[ebase + lm],      src1 = ei[ebase + 16 + lm];
    int dst0 = ei[E + ebase + lm],  dst1 = ei[E + ebase + 16 + lm];
    // Build A fragments: a[mt][s] holds h1[edge lm (+16*mt)][k = s*32+lg*8 .. +8]
    Frag a[2][4];
    #pragma unroll
    for (int s = 0; s < 4; ++s) {
      const int off = s*64 + lg*16;  // byte offset into 256B row
      #pragma unroll
      for (int mt = 0; mt < 2; ++mt) {
        int sn = mt ? src1 : src0;
        int dn = mt ? dst1 : dst0;
        u32x4 ua = *(const u32x4*)((const char*)T1 + (size_t)sn*256 + off);
        u32x4 ub = *(const u32x4*)((const char*)T2 + (size_t)dn*256 + off);
        Frag fa;
        #pragma unroll
        for (int q = 0; q < 4; ++q) {
          float v0 = fmaxf(bflo(ua[q]) + bflo(ub[q]), 0.f);
          float v1 = fmaxf(bfhi(ua[q]) + bfhi(ub[q]), 0.f);
          fa.s[2*q]   = f2bf(v0);
          fa.s[2*q+1] = f2bf(v1);
        }
        a[mt][s].q = fa.q;
      }
    }
    // MFMA: acc[mt][nt] = h1_tile(16x128) @ W2t'(128x16 per nt)
    f32x4 acc[2][8];
    #pragma unroll
    for (int mt = 0; mt < 2; ++mt)
      #pragma unroll
      for (int nt = 0; nt < 8; ++nt) {
        f32x4 zed = {0.f, 0.f, 0.f, 0.f};
        acc[mt][nt] = zed;
      }
    #pragma unroll
    for (int nt = 0; nt < 8; ++nt) {
      #pragma unroll
      for (int s = 0; s < 4; ++s) {
        int idx16 = (nt*16 + lm)*16 + (((s*4 + lg)) ^ (lm & 7));
        Frag bf; bf.q = w2l[idx16];
        acc[0][nt] = __builtin_amdgcn_mfma_f32_16x16x32_bf16(a[0][s].b, bf.b, acc[0][nt], 0, 0, 0);
        acc[1][nt] = __builtin_amdgcn_mfma_f32_16x16x32_bf16(a[1][s].b, bf.b, acc[1][nt], 0, 0, 0);
      }
    }
    // Epilogue: h2 = relu(acc + b2p); logit = sum_n h2*W3 (+b3)
    #pragma unroll
    for (int mt = 0; mt < 2; ++mt) {
      #pragma unroll
      for (int r = 0; r < 4; ++r) {
        float sum = 0.f;
        #pragma unroll
        for (int nt = 0; nt < 8; ++nt) {
          float h2 = fmaxf(acc[mt][nt][r] + b2r[nt], 0.f);
          sum += h2 * w3r[nt];
        }
        sum += __shfl_xor(sum, 1, 64);
        sum += __shfl_xor(sum, 2, 64);
        sum += __shfl_xor(sum, 4, 64);
        sum += __shfl_xor(sum, 8, 64);
        if (lm == 0) out[ebase + mt*16 + lg*4 + r] = sum + b3v;
      }
    }
  }
}

extern "C" void kernel_launch(void* const* d_in, const int* in_sizes, int n_in,
                              void* d_out, int out_size, void* d_ws, size_t ws_size,
                              hipStream_t stream) {
  const float* z     = (const float*)d_in[0];
  const int*   ei    = (const int*)d_in[1];
  const float* c     = (const float*)d_in[2];
  const float* W1    = (const float*)d_in[3];
  const float* b1    = (const float*)d_in[4];
  const float* gamma = (const float*)d_in[5];
  const float* beta  = (const float*)d_in[6];
  const float* W2    = (const float*)d_in[7];
  const float* b2    = (const float*)d_in[8];
  const float* W3    = (const float*)d_in[9];
  const float* b3    = (const float*)d_in[10];
  float* out = (float*)d_out;

  const int n_nodes = in_sizes[0] / 64;   // 50000
  const int E       = in_sizes[1] / 2;    // 1600000

  const int NB2 = 1024;   // stats blocks
  const int NB4 = 1024;   // edge blocks

  char* ws = (char*)d_ws;
  const size_t t1b = (size_t)n_nodes * 128 * 2;           // bf16 table bytes
  unsigned short* T1 = (unsigned short*)ws;
  unsigned short* T2 = (unsigned short*)(ws + t1b);
  float* partial     = (float*)(ws + 2*t1b);              // NB2*256 f32
  unsigned short* W2t= (unsigned short*)(ws + 2*t1b + (size_t)NB2*1024);
  float* b2p         = (float*)(ws + 2*t1b + (size_t)NB2*1024 + 32768);

  k_nodeproj<<<(n_nodes + 255)/256, 256, 0, stream>>>(z, c, W1, b1, T1, T2, n_nodes);
  k_stats<<<NB2, 256, 0, stream>>>(ei, T1, T2, partial, E, E/2);
  k_finalize<<<1, 1024, 0, stream>>>(partial, NB2, gamma, beta, W2, b2, W2t, b2p, 1.0f/(float)E);
  k_edge<<<NB4, 256, 0, stream>>>(ei, T1, T2, W2t, b2p, W3, b3, out, E, E/128);
}

// Round 4
// 408.060 us; speedup vs baseline: 1.7680x; 1.3544x over previous
//
#include <hip/hip_runtime.h>
#include <stdint.h>

#define BN_EPS 1e-5f

typedef __bf16   bf16x8 __attribute__((ext_vector_type(8)));
typedef float    f32x4  __attribute__((ext_vector_type(4)));
typedef unsigned u32x4  __attribute__((ext_vector_type(4)));
typedef unsigned u32x2  __attribute__((ext_vector_type(2)));

union Frag {
  u32x4 q;
  bf16x8 b;
  unsigned short s[8];
  unsigned u[4];
};

static __device__ __forceinline__ unsigned short f2bf(float f) {
  union { float f; unsigned u; } v; v.f = f;
  unsigned r = (v.u + 0x7fffu + ((v.u >> 16) & 1u)) >> 16;   // RNE
  return (unsigned short)r;
}
static __device__ __forceinline__ float bflo(unsigned u) {
  union { unsigned u; float f; } v; v.u = u << 16; return v.f;
}
static __device__ __forceinline__ float bfhi(unsigned u) {
  union { unsigned u; float f; } v; v.u = u & 0xffff0000u; return v.f;
}
static __device__ __forceinline__ unsigned packbf(float lo, float hi) {
  // native casts -> compiler emits v_cvt_pk_bf16_f32 (RNE)
  __bf16 a = (__bf16)lo, b = (__bf16)hi;
  unsigned short x = __builtin_bit_cast(unsigned short, a);
  unsigned short y = __builtin_bit_cast(unsigned short, b);
  return (unsigned)x | ((unsigned)y << 16);
}

// ---------------- kernel 1: per-node projections -------------------
// T1[n][k] = sum_d z[n][d]*W1[d][k] + kv[k]   (kv = c @ W1[128:132] + b1 folded in)
// T2[n][k] = sum_d z[n][d]*W1[64+d][k]
__global__ __launch_bounds__(256) void k_nodeproj(
    const float* __restrict__ z, const float* __restrict__ c,
    const float* __restrict__ W1, const float* __restrict__ b1,
    unsigned short* __restrict__ T1, unsigned short* __restrict__ T2,
    int n_nodes) {
  __shared__ float Wl[64][128];   // 32 KB
  __shared__ float kv[128];
  const int t = threadIdx.x;
  if (t < 128) {
    float acc = b1[t];
    #pragma unroll
    for (int q = 0; q < 4; ++q) acc += c[q] * W1[(128 + q) * 128 + t];
    kv[t] = acc;
  }
  for (int i = t; i < 8192; i += 256) Wl[i >> 7][i & 127] = W1[i];
  __syncthreads();
  const int n = blockIdx.x * 256 + t;
  const bool act = (n < n_nodes);
  float zr[64];
  if (act) {
    const f32x4* zp = (const f32x4*)(z + (size_t)n * 64);
    #pragma unroll
    for (int j = 0; j < 16; ++j) {
      f32x4 v = zp[j];
      zr[4*j+0] = v[0]; zr[4*j+1] = v[1]; zr[4*j+2] = v[2]; zr[4*j+3] = v[3];
    }
  }
  if (act) {
    for (int k8 = 0; k8 < 16; ++k8) {
      float acc[8];
      f32x4 k0 = *(const f32x4*)&kv[k8*8];
      f32x4 k1 = *(const f32x4*)&kv[k8*8+4];
      acc[0]=k0[0]; acc[1]=k0[1]; acc[2]=k0[2]; acc[3]=k0[3];
      acc[4]=k1[0]; acc[5]=k1[1]; acc[6]=k1[2]; acc[7]=k1[3];
      #pragma unroll
      for (int d = 0; d < 64; ++d) {
        float zd = zr[d];
        f32x4 wa = *(const f32x4*)&Wl[d][k8*8];
        f32x4 wb = *(const f32x4*)&Wl[d][k8*8+4];
        acc[0] += zd*wa[0]; acc[1] += zd*wa[1]; acc[2] += zd*wa[2]; acc[3] += zd*wa[3];
        acc[4] += zd*wb[0]; acc[5] += zd*wb[1]; acc[6] += zd*wb[2]; acc[7] += zd*wb[3];
      }
      Frag f;
      #pragma unroll
      for (int j = 0; j < 8; ++j) f.s[j] = f2bf(acc[j]);
      *(u32x4*)(T1 + (size_t)n*128 + k8*8) = f.q;
    }
  }
  __syncthreads();
  for (int i = t; i < 8192; i += 256) Wl[i >> 7][i & 127] = W1[8192 + i];
  __syncthreads();
  if (act) {
    for (int k8 = 0; k8 < 16; ++k8) {
      float acc[8] = {0,0,0,0,0,0,0,0};
      #pragma unroll
      for (int d = 0; d < 64; ++d) {
        float zd = zr[d];
        f32x4 wa = *(const f32x4*)&Wl[d][k8*8];
        f32x4 wb = *(const f32x4*)&Wl[d][k8*8+4];
        acc[0] += zd*wa[0]; acc[1] += zd*wa[1]; acc[2] += zd*wa[2]; acc[3] += zd*wa[3];
        acc[4] += zd*wb[0]; acc[5] += zd*wb[1]; acc[6] += zd*wb[2]; acc[7] += zd*wb[3];
      }
      Frag f;
      #pragma unroll
      for (int j = 0; j < 8; ++j) f.s[j] = f2bf(acc[j]);
      *(u32x4*)(T2 + (size_t)n*128 + k8*8) = f.q;
    }
  }
}

// ---------------- kernel 2: BN statistics pass ---------------------
// 512-thread blocks, 8 waves. Wave-iter handles 8 edges: lane (es=l>>4, lm=l&15)
// gathers 16B (8 features) of T1[src]/T2[dst] for edges e8+es and e8+4+es.
// Lane exclusively owns features lm*8..lm*8+7 -> 8 sum + 8 sumsq accumulators.
__global__ __launch_bounds__(512) void k_stats(
    const int* __restrict__ ei, const unsigned short* __restrict__ T1,
    const unsigned short* __restrict__ T2, float* __restrict__ partial,
    int E, int niter8) {
  __shared__ float red[8][256];
  const int t = threadIdx.x;
  const int w = t >> 6, l = t & 63;
  const int es = l >> 4, lm = l & 15;
  float sm[8] = {0,0,0,0,0,0,0,0};
  float sq[8] = {0,0,0,0,0,0,0,0};
  const int nw = gridDim.x * 8;
  for (int it = blockIdx.x * 8 + w; it < niter8; it += nw) {
    const int e8 = it * 8;
    int s0 = ei[e8 + es];
    int d0 = ei[E + e8 + es];
    int s1 = ei[e8 + 4 + es];
    int d1 = ei[E + e8 + 4 + es];
    u32x4 a0 = *(const u32x4*)((const char*)T1 + (size_t)s0*256 + lm*16);
    u32x4 b0 = *(const u32x4*)((const char*)T2 + (size_t)d0*256 + lm*16);
    u32x4 a1 = *(const u32x4*)((const char*)T1 + (size_t)s1*256 + lm*16);
    u32x4 b1 = *(const u32x4*)((const char*)T2 + (size_t)d1*256 + lm*16);
    #pragma unroll
    for (int q = 0; q < 4; ++q) {
      float h0 = fmaxf(bflo(a0[q]) + bflo(b0[q]), 0.f);
      float h1 = fmaxf(bfhi(a0[q]) + bfhi(b0[q]), 0.f);
      float g0 = fmaxf(bflo(a1[q]) + bflo(b1[q]), 0.f);
      float g1 = fmaxf(bfhi(a1[q]) + bfhi(b1[q]), 0.f);
      sm[2*q]   += h0 + g0; sq[2*q]   += h0*h0 + g0*g0;
      sm[2*q+1] += h1 + g1; sq[2*q+1] += h1*h1 + g1*g1;
    }
  }
  // reduce over the 4 es-groups (feature lm*8+q owned by lanes sharing lm)
  #pragma unroll
  for (int q = 0; q < 8; ++q) {
    sm[q] += __shfl_xor(sm[q], 16, 64);
    sm[q] += __shfl_xor(sm[q], 32, 64);
    sq[q] += __shfl_xor(sq[q], 16, 64);
    sq[q] += __shfl_xor(sq[q], 32, 64);
  }
  if (es == 0) {
    #pragma unroll
    for (int q = 0; q < 8; ++q) {
      red[w][lm*8 + q]       = sm[q];
      red[w][128 + lm*8 + q] = sq[q];
    }
  }
  __syncthreads();
  if (t < 256) {
    float s = 0.f;
    #pragma unroll
    for (int ww = 0; ww < 8; ++ww) s += red[ww][t];
    partial[(size_t)blockIdx.x * 256 + t] = s;
  }
}

// ---------------- kernel 3: finalize BN + fold into W2 -------------
__global__ __launch_bounds__(1024) void k_finalize(
    const float* __restrict__ partial, int nb,
    const float* __restrict__ gamma, const float* __restrict__ beta,
    const float* __restrict__ W2, const float* __restrict__ b2,
    unsigned short* __restrict__ W2t, float* __restrict__ b2p, float Einv) {
  __shared__ float red[4][256];
  __shared__ float stat[256];
  __shared__ float aj[128], bbj[128];
  __shared__ float bacc[8][128];
  const int t = threadIdx.x;
  const int slot = t & 255, g = t >> 8;           // g = 0..3
  float s = 0.f;
  for (int b = g; b < nb; b += 4) s += partial[(size_t)b * 256 + slot];
  red[g][slot] = s;
  __syncthreads();
  if (t < 256) stat[t] = red[0][t] + red[1][t] + red[2][t] + red[3][t];
  __syncthreads();
  if (t < 128) {
    float mean = stat[t] * Einv;
    float var  = stat[128 + t] * Einv - mean * mean;
    float a = gamma[t] * rsqrtf(var + BN_EPS);
    aj[t] = a;
    bbj[t] = beta[t] - mean * a;
  }
  __syncthreads();
  for (int cidx = t; cidx < 16384; cidx += 1024) {
    int i = cidx >> 7;     // input feature (W2 row)
    int j = cidx & 127;    // output column (W2t row)
    W2t[j * 128 + i] = f2bf(aj[i] * W2[cidx]);
  }
  {
    const int col = t & 127, g2 = t >> 7;         // g2 = 0..7
    float acc = 0.f;
    #pragma unroll
    for (int q = 0; q < 16; ++q) {
      int i = g2 * 16 + q;
      acc += bbj[i] * W2[i * 128 + col];
    }
    bacc[g2][col] = acc;
  }
  __syncthreads();
  if (t < 128) {
    float a = b2[t];
    #pragma unroll
    for (int g3 = 0; g3 < 8; ++g3) a += bacc[g3][t];
    b2p[t] = a;
  }
}

// ---------------- kernel 4: per-edge MFMA pass (prefetch-pipelined) ----
// Wave: 32 edges x 128 outputs. Per s-group: repack staged gathers -> A frags,
// RE-ISSUE that s-group's gathers for the next tile, then its 16 MFMAs.
// Gather latency hides under the compute of the current tile.
__global__ __launch_bounds__(256) void k_edge(
    const int* __restrict__ ei, const unsigned short* __restrict__ T1,
    const unsigned short* __restrict__ T2, const unsigned short* __restrict__ W2t,
    const float* __restrict__ b2p, const float* __restrict__ W3,
    const float* __restrict__ b3, float* __restrict__ out,
    int E, int ntiles) {
  __shared__ u32x4 w2l[2048];   // 32 KB, XOR-swizzled [n][k] bf16
  const int t = threadIdx.x;
  for (int cchunk = t; cchunk < 2048; cchunk += 256) {
    int n = cchunk >> 4;
    int koff = (cchunk & 15) << 4;               // byte offset within 256B row
    int swz = koff ^ ((n & 7) << 4);
    w2l[n*16 + (swz >> 4)] =
        *(const u32x4*)((const char*)W2t + (size_t)n*256 + koff);
  }
  __syncthreads();
  const int w = t >> 6, l = t & 63;
  const int lm = l & 15, lg = l >> 4;
  float b2r[8], w3r[8];
  #pragma unroll
  for (int nt = 0; nt < 8; ++nt) {
    b2r[nt] = b2p[nt*16 + lm];
    w3r[nt] = W3[nt*16 + lm];
  }
  const float b3v = *b3;
  const int stride = gridDim.x;
  int tile = blockIdx.x;
  if (tile >= ntiles) return;
  int ebase = tile*128 + w*32;
  u32x4 ua0[4], ua1[4], ub0[4], ub1[4];          // staged gathers (current tile)
  {
    int src0 = ei[ebase + lm],     src1 = ei[ebase + 16 + lm];
    int dst0 = ei[E + ebase + lm], dst1 = ei[E + ebase + 16 + lm];
    #pragma unroll
    for (int s = 0; s < 4; ++s) {
      const int o = s*64 + lg*16;
      ua0[s] = *(const u32x4*)((const char*)T1 + (size_t)src0*256 + o);
      ub0[s] = *(const u32x4*)((const char*)T2 + (size_t)dst0*256 + o);
      ua1[s] = *(const u32x4*)((const char*)T1 + (size_t)src1*256 + o);
      ub1[s] = *(const u32x4*)((const char*)T2 + (size_t)dst1*256 + o);
    }
  }
  while (true) {
    const int next = tile + stride;
    const bool has_next = next < ntiles;
    const int pref = has_next ? next : tile;     // clamped (last iter: dummy)
    const int neb = pref*128 + w*32;
    int nsrc0 = ei[neb + lm],     nsrc1 = ei[neb + 16 + lm];
    int ndst0 = ei[E + neb + lm], ndst1 = ei[E + neb + 16 + lm];
    f32x4 acc[2][8];
    #pragma unroll
    for (int mt = 0; mt < 2; ++mt)
      #pragma unroll
      for (int nt = 0; nt < 8; ++nt) {
        f32x4 zed = {0.f, 0.f, 0.f, 0.f};
        acc[mt][nt] = zed;
      }
    #pragma unroll
    for (int s = 0; s < 4; ++s) {
      // repack staged s-group into A fragments
      Frag a0, a1;
      #pragma unroll
      for (int q = 0; q < 4; ++q) {
        a0.u[q] = packbf(fmaxf(bflo(ua0[s][q]) + bflo(ub0[s][q]), 0.f),
                         fmaxf(bfhi(ua0[s][q]) + bfhi(ub0[s][q]), 0.f));
        a1.u[q] = packbf(fmaxf(bflo(ua1[s][q]) + bflo(ub1[s][q]), 0.f),
                         fmaxf(bfhi(ua1[s][q]) + bfhi(ub1[s][q]), 0.f));
      }
      // re-issue this s-group's gathers for the next tile (latency hides
      // under the MFMAs below + remaining s-groups + epilogue)
      {
        const int o = s*64 + lg*16;
        ua0[s] = *(const u32x4*)((const char*)T1 + (size_t)nsrc0*256 + o);
        ub0[s] = *(const u32x4*)((const char*)T2 + (size_t)ndst0*256 + o);
        ua1[s] = *(const u32x4*)((const char*)T1 + (size_t)nsrc1*256 + o);
        ub1[s] = *(const u32x4*)((const char*)T2 + (size_t)ndst1*256 + o);
      }
      // MFMAs for this s-group
      #pragma unroll
      for (int nt = 0; nt < 8; ++nt) {
        int idx16 = (nt*16 + lm)*16 + ((s*4 + lg) ^ (lm & 7));
        Frag bf; bf.q = w2l[idx16];
        acc[0][nt] = __builtin_amdgcn_mfma_f32_16x16x32_bf16(a0.b, bf.b, acc[0][nt], 0, 0, 0);
        acc[1][nt] = __builtin_amdgcn_mfma_f32_16x16x32_bf16(a1.b, bf.b, acc[1][nt], 0, 0, 0);
      }
    }
    // Epilogue: h2 = relu(acc + b2p); logit = sum_n h2*W3 (+b3)
    #pragma unroll
    for (int mt = 0; mt < 2; ++mt) {
      #pragma unroll
      for (int r = 0; r < 4; ++r) {
        float sum = 0.f;
        #pragma unroll
        for (int nt = 0; nt < 8; ++nt) {
          float h2 = fmaxf(acc[mt][nt][r] + b2r[nt], 0.f);
          sum += h2 * w3r[nt];
        }
        sum += __shfl_xor(sum, 1, 64);
        sum += __shfl_xor(sum, 2, 64);
        sum += __shfl_xor(sum, 4, 64);
        sum += __shfl_xor(sum, 8, 64);
        if (lm == 0) out[ebase + mt*16 + lg*4 + r] = sum + b3v;
      }
    }
    if (!has_next) break;
    tile = next;
    ebase = neb;
  }
}

extern "C" void kernel_launch(void* const* d_in, const int* in_sizes, int n_in,
                              void* d_out, int out_size, void* d_ws, size_t ws_size,
                              hipStream_t stream) {
  const float* z     = (const float*)d_in[0];
  const int*   ei    = (const int*)d_in[1];
  const float* c     = (const float*)d_in[2];
  const float* W1    = (const float*)d_in[3];
  const float* b1    = (const float*)d_in[4];
  const float* gamma = (const float*)d_in[5];
  const float* beta  = (const float*)d_in[6];
  const float* W2    = (const float*)d_in[7];
  const float* b2    = (const float*)d_in[8];
  const float* W3    = (const float*)d_in[9];
  const float* b3    = (const float*)d_in[10];
  float* out = (float*)d_out;

  const int n_nodes = in_sizes[0] / 64;   // 50000
  const int E       = in_sizes[1] / 2;    // 1600000

  const int NB2 = 1024;   // stats blocks (512 thr = 8 waves each)
  const int NB4 = 1024;   // edge blocks

  char* ws = (char*)d_ws;
  const size_t t1b = (size_t)n_nodes * 128 * 2;           // bf16 table bytes
  unsigned short* T1 = (unsigned short*)ws;
  unsigned short* T2 = (unsigned short*)(ws + t1b);
  float* partial     = (float*)(ws + 2*t1b);              // NB2*256 f32
  unsigned short* W2t= (unsigned short*)(ws + 2*t1b + (size_t)NB2*1024);
  float* b2p         = (float*)(ws + 2*t1b + (size_t)NB2*1024 + 32768);

  k_nodeproj<<<(n_nodes + 255)/256, 256, 0, stream>>>(z, c, W1, b1, T1, T2, n_nodes);
  k_stats<<<NB2, 512, 0, stream>>>(ei, T1, T2, partial, E, E/8);
  k_finalize<<<1, 1024, 0, stream>>>(partial, NB2, gamma, beta, W2, b2, W2t, b2p, 1.0f/(float)E);
  k_edge<<<NB4, 256, 0, stream>>>(ei, T1, T2, W2t, b2p, W3, b3, out, E, E/128);
}

// Round 5
// 407.041 us; speedup vs baseline: 1.7724x; 1.0025x over previous
//
#include <hip/hip_runtime.h>
#include <stdint.h>

#define BN_EPS 1e-5f

typedef __bf16   bf16x8 __attribute__((ext_vector_type(8)));
typedef float    f32x4  __attribute__((ext_vector_type(4)));
typedef unsigned u32x4  __attribute__((ext_vector_type(4)));
typedef unsigned u32x2  __attribute__((ext_vector_type(2)));

union Frag {
  u32x4 q;
  bf16x8 b;
  unsigned short s[8];
  unsigned u[4];
};

static __device__ __forceinline__ unsigned short f2bf(float f) {
  union { float f; unsigned u; } v; v.f = f;
  unsigned r = (v.u + 0x7fffu + ((v.u >> 16) & 1u)) >> 16;   // RNE
  return (unsigned short)r;
}
static __device__ __forceinline__ float bflo(unsigned u) {
  union { unsigned u; float f; } v; v.u = u << 16; return v.f;
}
static __device__ __forceinline__ float bfhi(unsigned u) {
  union { unsigned u; float f; } v; v.u = u & 0xffff0000u; return v.f;
}
static __device__ __forceinline__ unsigned packbf(float lo, float hi) {
  // native casts -> compiler emits v_cvt_pk_bf16_f32 (RNE)
  __bf16 a = (__bf16)lo, b = (__bf16)hi;
  unsigned short x = __builtin_bit_cast(unsigned short, a);
  unsigned short y = __builtin_bit_cast(unsigned short, b);
  return (unsigned)x | ((unsigned)y << 16);
}

// ---------------- kernel 1: per-node projections -------------------
// T1[n][k] = sum_d z[n][d]*W1[d][k] + kv[k]   (kv = c @ W1[128:132] + b1 folded in)
// T2[n][k] = sum_d z[n][d]*W1[64+d][k]
__global__ __launch_bounds__(256) void k_nodeproj(
    const float* __restrict__ z, const float* __restrict__ c,
    const float* __restrict__ W1, const float* __restrict__ b1,
    unsigned short* __restrict__ T1, unsigned short* __restrict__ T2,
    int n_nodes) {
  __shared__ float Wl[64][128];   // 32 KB
  __shared__ float kv[128];
  const int t = threadIdx.x;
  if (t < 128) {
    float acc = b1[t];
    #pragma unroll
    for (int q = 0; q < 4; ++q) acc += c[q] * W1[(128 + q) * 128 + t];
    kv[t] = acc;
  }
  for (int i = t; i < 8192; i += 256) Wl[i >> 7][i & 127] = W1[i];
  __syncthreads();
  const int n = blockIdx.x * 256 + t;
  const bool act = (n < n_nodes);
  float zr[64];
  if (act) {
    const f32x4* zp = (const f32x4*)(z + (size_t)n * 64);
    #pragma unroll
    for (int j = 0; j < 16; ++j) {
      f32x4 v = zp[j];
      zr[4*j+0] = v[0]; zr[4*j+1] = v[1]; zr[4*j+2] = v[2]; zr[4*j+3] = v[3];
    }
  }
  if (act) {
    for (int k8 = 0; k8 < 16; ++k8) {
      float acc[8];
      f32x4 k0 = *(const f32x4*)&kv[k8*8];
      f32x4 k1 = *(const f32x4*)&kv[k8*8+4];
      acc[0]=k0[0]; acc[1]=k0[1]; acc[2]=k0[2]; acc[3]=k0[3];
      acc[4]=k1[0]; acc[5]=k1[1]; acc[6]=k1[2]; acc[7]=k1[3];
      #pragma unroll
      for (int d = 0; d < 64; ++d) {
        float zd = zr[d];
        f32x4 wa = *(const f32x4*)&Wl[d][k8*8];
        f32x4 wb = *(const f32x4*)&Wl[d][k8*8+4];
        acc[0] += zd*wa[0]; acc[1] += zd*wa[1]; acc[2] += zd*wa[2]; acc[3] += zd*wa[3];
        acc[4] += zd*wb[0]; acc[5] += zd*wb[1]; acc[6] += zd*wb[2]; acc[7] += zd*wb[3];
      }
      Frag f;
      #pragma unroll
      for (int j = 0; j < 8; ++j) f.s[j] = f2bf(acc[j]);
      *(u32x4*)(T1 + (size_t)n*128 + k8*8) = f.q;
    }
  }
  __syncthreads();
  for (int i = t; i < 8192; i += 256) Wl[i >> 7][i & 127] = W1[8192 + i];
  __syncthreads();
  if (act) {
    for (int k8 = 0; k8 < 16; ++k8) {
      float acc[8] = {0,0,0,0,0,0,0,0};
      #pragma unroll
      for (int d = 0; d < 64; ++d) {
        float zd = zr[d];
        f32x4 wa = *(const f32x4*)&Wl[d][k8*8];
        f32x4 wb = *(const f32x4*)&Wl[d][k8*8+4];
        acc[0] += zd*wa[0]; acc[1] += zd*wa[1]; acc[2] += zd*wa[2]; acc[3] += zd*wa[3];
        acc[4] += zd*wb[0]; acc[5] += zd*wb[1]; acc[6] += zd*wb[2]; acc[7] += zd*wb[3];
      }
      Frag f;
      #pragma unroll
      for (int j = 0; j < 8; ++j) f.s[j] = f2bf(acc[j]);
      *(u32x4*)(T2 + (size_t)n*128 + k8*8) = f.q;
    }
  }
}

// ---------------- kernel 2: BN statistics pass (+ optional H1 store) ----
// 512-thread blocks, 8 waves. Wave-iter handles 8 edges: lane (es=l>>4, lm=l&15)
// gathers 16B (8 features) of T1[src]/T2[dst] for edges e8+es and e8+4+es.
// Lane exclusively owns features lm*8..lm*8+7 -> 8 sum + 8 sumsq accumulators.
// If WH1: also store h1 = bf16(relu(T1[src]+T2[dst])) row-major [E][128].
template<bool WH1>
__global__ __launch_bounds__(512) void k_stats(
    const int* __restrict__ ei, const unsigned short* __restrict__ T1,
    const unsigned short* __restrict__ T2, float* __restrict__ partial,
    unsigned short* __restrict__ H1, int E, int niter8) {
  __shared__ float red[8][256];
  const int t = threadIdx.x;
  const int w = t >> 6, l = t & 63;
  const int es = l >> 4, lm = l & 15;
  float sm[8] = {0,0,0,0,0,0,0,0};
  float sq[8] = {0,0,0,0,0,0,0,0};
  const int nw = gridDim.x * 8;
  for (int it = blockIdx.x * 8 + w; it < niter8; it += nw) {
    const int e8 = it * 8;
    int s0 = ei[e8 + es];
    int d0 = ei[E + e8 + es];
    int s1 = ei[e8 + 4 + es];
    int d1 = ei[E + e8 + 4 + es];
    u32x4 a0 = *(const u32x4*)((const char*)T1 + (size_t)s0*256 + lm*16);
    u32x4 b0 = *(const u32x4*)((const char*)T2 + (size_t)d0*256 + lm*16);
    u32x4 a1 = *(const u32x4*)((const char*)T1 + (size_t)s1*256 + lm*16);
    u32x4 b1 = *(const u32x4*)((const char*)T2 + (size_t)d1*256 + lm*16);
    u32x4 pa, pb;
    #pragma unroll
    for (int q = 0; q < 4; ++q) {
      float h0 = fmaxf(bflo(a0[q]) + bflo(b0[q]), 0.f);
      float h1 = fmaxf(bfhi(a0[q]) + bfhi(b0[q]), 0.f);
      float g0 = fmaxf(bflo(a1[q]) + bflo(b1[q]), 0.f);
      float g1 = fmaxf(bfhi(a1[q]) + bfhi(b1[q]), 0.f);
      sm[2*q]   += h0 + g0; sq[2*q]   += h0*h0 + g0*g0;
      sm[2*q+1] += h1 + g1; sq[2*q+1] += h1*h1 + g1*g1;
      if (WH1) { pa[q] = packbf(h0, h1); pb[q] = packbf(g0, g1); }
    }
    if (WH1) {
      *(u32x4*)((char*)H1 + (size_t)(e8 + es)*256 + lm*16)     = pa;
      *(u32x4*)((char*)H1 + (size_t)(e8 + 4 + es)*256 + lm*16) = pb;
    }
  }
  // reduce over the 4 es-groups (feature lm*8+q owned by lanes sharing lm)
  #pragma unroll
  for (int q = 0; q < 8; ++q) {
    sm[q] += __shfl_xor(sm[q], 16, 64);
    sm[q] += __shfl_xor(sm[q], 32, 64);
    sq[q] += __shfl_xor(sq[q], 16, 64);
    sq[q] += __shfl_xor(sq[q], 32, 64);
  }
  if (es == 0) {
    #pragma unroll
    for (int q = 0; q < 8; ++q) {
      red[w][lm*8 + q]       = sm[q];
      red[w][128 + lm*8 + q] = sq[q];
    }
  }
  __syncthreads();
  if (t < 256) {
    float s = 0.f;
    #pragma unroll
    for (int ww = 0; ww < 8; ++ww) s += red[ww][t];
    partial[(size_t)blockIdx.x * 256 + t] = s;
  }
}

// ---------------- kernel 3: finalize BN + fold into W2 -------------
__global__ __launch_bounds__(1024) void k_finalize(
    const float* __restrict__ partial, int nb,
    const float* __restrict__ gamma, const float* __restrict__ beta,
    const float* __restrict__ W2, const float* __restrict__ b2,
    unsigned short* __restrict__ W2t, float* __restrict__ b2p, float Einv) {
  __shared__ float red[4][256];
  __shared__ float stat[256];
  __shared__ float aj[128], bbj[128];
  __shared__ float bacc[8][128];
  const int t = threadIdx.x;
  const int slot = t & 255, g = t >> 8;           // g = 0..3
  float s = 0.f;
  for (int b = g; b < nb; b += 4) s += partial[(size_t)b * 256 + slot];
  red[g][slot] = s;
  __syncthreads();
  if (t < 256) stat[t] = red[0][t] + red[1][t] + red[2][t] + red[3][t];
  __syncthreads();
  if (t < 128) {
    float mean = stat[t] * Einv;
    float var  = stat[128 + t] * Einv - mean * mean;
    float a = gamma[t] * rsqrtf(var + BN_EPS);
    aj[t] = a;
    bbj[t] = beta[t] - mean * a;
  }
  __syncthreads();
  for (int cidx = t; cidx < 16384; cidx += 1024) {
    int i = cidx >> 7;     // input feature (W2 row)
    int j = cidx & 127;    // output column (W2t row)
    W2t[j * 128 + i] = f2bf(aj[i] * W2[cidx]);
  }
  {
    const int col = t & 127, g2 = t >> 7;         // g2 = 0..7
    float acc = 0.f;
    #pragma unroll
    for (int q = 0; q < 16; ++q) {
      int i = g2 * 16 + q;
      acc += bbj[i] * W2[i * 128 + col];
    }
    bacc[g2][col] = acc;
  }
  __syncthreads();
  if (t < 128) {
    float a = b2[t];
    #pragma unroll
    for (int g3 = 0; g3 < 8; ++g3) a += bacc[g3][t];
    b2p[t] = a;
  }
}

// ---------------- kernel 4a: streaming MFMA pass over materialized H1 ----
// Wave: 32 edges x 128 outputs. A-frags are direct 16B linear loads from H1
// (no gathers, no repack); B (W2t) in XOR-swizzled LDS; fused relu+W3 epilogue.
__global__ __launch_bounds__(256) void k_edge_h1(
    const unsigned short* __restrict__ H1, const unsigned short* __restrict__ W2t,
    const float* __restrict__ b2p, const float* __restrict__ W3,
    const float* __restrict__ b3, float* __restrict__ out, int ntiles) {
  __shared__ u32x4 w2l[2048];   // 32 KB, XOR-swizzled [n][k] bf16
  const int t = threadIdx.x;
  for (int cchunk = t; cchunk < 2048; cchunk += 256) {
    int n = cchunk >> 4;
    int koff = (cchunk & 15) << 4;
    int swz = koff ^ ((n & 7) << 4);
    w2l[n*16 + (swz >> 4)] =
        *(const u32x4*)((const char*)W2t + (size_t)n*256 + koff);
  }
  __syncthreads();
  const int w = t >> 6, l = t & 63;
  const int lm = l & 15, lg = l >> 4;
  float b2r[8], w3r[8];
  #pragma unroll
  for (int nt = 0; nt < 8; ++nt) {
    b2r[nt] = b2p[nt*16 + lm];
    w3r[nt] = W3[nt*16 + lm];
  }
  const float b3v = *b3;
  for (int tile = blockIdx.x; tile < ntiles; tile += gridDim.x) {
    const int ebase = tile*128 + w*32;
    const char* rb = (const char*)H1 + (size_t)ebase*256;
    Frag a0[4], a1[4];
    #pragma unroll
    for (int s = 0; s < 4; ++s) {
      const int o = s*64 + lg*16;
      a0[s].q = *(const u32x4*)(rb + (size_t)lm*256 + o);
      a1[s].q = *(const u32x4*)(rb + (size_t)(lm + 16)*256 + o);
    }
    f32x4 acc[2][8];
    #pragma unroll
    for (int mt = 0; mt < 2; ++mt)
      #pragma unroll
      for (int nt = 0; nt < 8; ++nt) {
        f32x4 zed = {0.f, 0.f, 0.f, 0.f};
        acc[mt][nt] = zed;
      }
    #pragma unroll
    for (int nt = 0; nt < 8; ++nt) {
      #pragma unroll
      for (int s = 0; s < 4; ++s) {
        int idx16 = (nt*16 + lm)*16 + ((s*4 + lg) ^ (lm & 7));
        Frag bf; bf.q = w2l[idx16];
        acc[0][nt] = __builtin_amdgcn_mfma_f32_16x16x32_bf16(a0[s].b, bf.b, acc[0][nt], 0, 0, 0);
        acc[1][nt] = __builtin_amdgcn_mfma_f32_16x16x32_bf16(a1[s].b, bf.b, acc[1][nt], 0, 0, 0);
      }
    }
    #pragma unroll
    for (int mt = 0; mt < 2; ++mt) {
      #pragma unroll
      for (int r = 0; r < 4; ++r) {
        float sum = 0.f;
        #pragma unroll
        for (int nt = 0; nt < 8; ++nt) {
          float h2 = fmaxf(acc[mt][nt][r] + b2r[nt], 0.f);
          sum += h2 * w3r[nt];
        }
        sum += __shfl_xor(sum, 1, 64);
        sum += __shfl_xor(sum, 2, 64);
        sum += __shfl_xor(sum, 4, 64);
        sum += __shfl_xor(sum, 8, 64);
        if (lm == 0) out[ebase + mt*16 + lg*4 + r] = sum + b3v;
      }
    }
  }
}

// ---------------- kernel 4b: fallback gather MFMA pass (round-4) -------
__global__ __launch_bounds__(256) void k_edge_gather(
    const int* __restrict__ ei, const unsigned short* __restrict__ T1,
    const unsigned short* __restrict__ T2, const unsigned short* __restrict__ W2t,
    const float* __restrict__ b2p, const float* __restrict__ W3,
    const float* __restrict__ b3, float* __restrict__ out,
    int E, int ntiles) {
  __shared__ u32x4 w2l[2048];
  const int t = threadIdx.x;
  for (int cchunk = t; cchunk < 2048; cchunk += 256) {
    int n = cchunk >> 4;
    int koff = (cchunk & 15) << 4;
    int swz = koff ^ ((n & 7) << 4);
    w2l[n*16 + (swz >> 4)] =
        *(const u32x4*)((const char*)W2t + (size_t)n*256 + koff);
  }
  __syncthreads();
  const int w = t >> 6, l = t & 63;
  const int lm = l & 15, lg = l >> 4;
  float b2r[8], w3r[8];
  #pragma unroll
  for (int nt = 0; nt < 8; ++nt) {
    b2r[nt] = b2p[nt*16 + lm];
    w3r[nt] = W3[nt*16 + lm];
  }
  const float b3v = *b3;
  const int stride = gridDim.x;
  int tile = blockIdx.x;
  if (tile >= ntiles) return;
  int ebase = tile*128 + w*32;
  u32x4 ua0[4], ua1[4], ub0[4], ub1[4];
  {
    int src0 = ei[ebase + lm],     src1 = ei[ebase + 16 + lm];
    int dst0 = ei[E + ebase + lm], dst1 = ei[E + ebase + 16 + lm];
    #pragma unroll
    for (int s = 0; s < 4; ++s) {
      const int o = s*64 + lg*16;
      ua0[s] = *(const u32x4*)((const char*)T1 + (size_t)src0*256 + o);
      ub0[s] = *(const u32x4*)((const char*)T2 + (size_t)dst0*256 + o);
      ua1[s] = *(const u32x4*)((const char*)T1 + (size_t)src1*256 + o);
      ub1[s] = *(const u32x4*)((const char*)T2 + (size_t)dst1*256 + o);
    }
  }
  while (true) {
    const int next = tile + stride;
    const bool has_next = next < ntiles;
    const int pref = has_next ? next : tile;
    const int neb = pref*128 + w*32;
    int nsrc0 = ei[neb + lm],     nsrc1 = ei[neb + 16 + lm];
    int ndst0 = ei[E + neb + lm], ndst1 = ei[E + neb + 16 + lm];
    f32x4 acc[2][8];
    #pragma unroll
    for (int mt = 0; mt < 2; ++mt)
      #pragma unroll
      for (int nt = 0; nt < 8; ++nt) {
        f32x4 zed = {0.f, 0.f, 0.f, 0.f};
        acc[mt][nt] = zed;
      }
    #pragma unroll
    for (int s = 0; s < 4; ++s) {
      Frag a0, a1;
      #pragma unroll
      for (int q = 0; q < 4; ++q) {
        a0.u[q] = packbf(fmaxf(bflo(ua0[s][q]) + bflo(ub0[s][q]), 0.f),
                         fmaxf(bfhi(ua0[s][q]) + bfhi(ub0[s][q]), 0.f));
        a1.u[q] = packbf(fmaxf(bflo(ua1[s][q]) + bflo(ub1[s][q]), 0.f),
                         fmaxf(bfhi(ua1[s][q]) + bfhi(ub1[s][q]), 0.f));
      }
      {
        const int o = s*64 + lg*16;
        ua0[s] = *(const u32x4*)((const char*)T1 + (size_t)nsrc0*256 + o);
        ub0[s] = *(const u32x4*)((const char*)T2 + (size_t)ndst0*256 + o);
        ua1[s] = *(const u32x4*)((const char*)T1 + (size_t)nsrc1*256 + o);
        ub1[s] = *(const u32x4*)((const char*)T2 + (size_t)ndst1*256 + o);
      }
      #pragma unroll
      for (int nt = 0; nt < 8; ++nt) {
        int idx16 = (nt*16 + lm)*16 + ((s*4 + lg) ^ (lm & 7));
        Frag bf; bf.q = w2l[idx16];
        acc[0][nt] = __builtin_amdgcn_mfma_f32_16x16x32_bf16(a0.b, bf.b, acc[0][nt], 0, 0, 0);
        acc[1][nt] = __builtin_amdgcn_mfma_f32_16x16x32_bf16(a1.b, bf.b, acc[1][nt], 0, 0, 0);
      }
    }
    #pragma unroll
    for (int mt = 0; mt < 2; ++mt) {
      #pragma unroll
      for (int r = 0; r < 4; ++r) {
        float sum = 0.f;
        #pragma unroll
        for (int nt = 0; nt < 8; ++nt) {
          float h2 = fmaxf(acc[mt][nt][r] + b2r[nt], 0.f);
          sum += h2 * w3r[nt];
        }
        sum += __shfl_xor(sum, 1, 64);
        sum += __shfl_xor(sum, 2, 64);
        sum += __shfl_xor(sum, 4, 64);
        sum += __shfl_xor(sum, 8, 64);
        if (lm == 0) out[ebase + mt*16 + lg*4 + r] = sum + b3v;
      }
    }
    if (!has_next) break;
    tile = next;
    ebase = neb;
  }
}

extern "C" void kernel_launch(void* const* d_in, const int* in_sizes, int n_in,
                              void* d_out, int out_size, void* d_ws, size_t ws_size,
                              hipStream_t stream) {
  const float* z     = (const float*)d_in[0];
  const int*   ei    = (const int*)d_in[1];
  const float* c     = (const float*)d_in[2];
  const float* W1    = (const float*)d_in[3];
  const float* b1    = (const float*)d_in[4];
  const float* gamma = (const float*)d_in[5];
  const float* beta  = (const float*)d_in[6];
  const float* W2    = (const float*)d_in[7];
  const float* b2    = (const float*)d_in[8];
  const float* W3    = (const float*)d_in[9];
  const float* b3    = (const float*)d_in[10];
  float* out = (float*)d_out;

  const int n_nodes = in_sizes[0] / 64;   // 50000
  const int E       = in_sizes[1] / 2;    // 1600000

  const int NB2 = 1024;   // stats blocks (512 thr = 8 waves each)

  char* ws = (char*)d_ws;
  const size_t t1b = (size_t)n_nodes * 128 * 2;           // bf16 table bytes
  unsigned short* T1 = (unsigned short*)ws;
  unsigned short* T2 = (unsigned short*)(ws + t1b);
  float* partial     = (float*)(ws + 2*t1b);              // NB2*256 f32
  unsigned short* W2t= (unsigned short*)(ws + 2*t1b + (size_t)NB2*1024);
  float* b2p         = (float*)(ws + 2*t1b + (size_t)NB2*1024 + 32768);
  const size_t h1off = 2*t1b + (size_t)NB2*1024 + 32768 + 512;
  unsigned short* H1 = (unsigned short*)(ws + h1off);
  const size_t need  = h1off + (size_t)E * 128 * 2;       // ~436 MB
  const bool use_h1  = (ws_size >= need);

  k_nodeproj<<<(n_nodes + 255)/256, 256, 0, stream>>>(z, c, W1, b1, T1, T2, n_nodes);
  if (use_h1)
    k_stats<true ><<<NB2, 512, 0, stream>>>(ei, T1, T2, partial, H1, E, E/8);
  else
    k_stats<false><<<NB2, 512, 0, stream>>>(ei, T1, T2, partial, H1, E, E/8);
  k_finalize<<<1, 1024, 0, stream>>>(partial, NB2, gamma, beta, W2, b2, W2t, b2p, 1.0f/(float)E);
  if (use_h1)
    k_edge_h1<<<2048, 256, 0, stream>>>(H1, W2t, b2p, W3, b3, out, E/128);
  else
    k_edge_gather<<<1024, 256, 0, stream>>>(ei, T1, T2, W2t, b2p, W3, b3, out, E, E/128);
}